// Round 2
// baseline (372.558 us; speedup 1.0000x reference)
//
#include <hip/hip_runtime.h>
#include <hip/hip_bf16.h>

typedef __hip_bfloat16 bf16;
using bf16x8 = __attribute__((ext_vector_type(8))) short;
using f32x4  = __attribute__((ext_vector_type(4))) float;
using f32x16 = __attribute__((ext_vector_type(16))) float;
using u32x4  = __attribute__((ext_vector_type(4))) unsigned int;

#define TSEQ 2048
#define NH   16
#define HD   64
#define NC   1024
#define DFF  4096
#define NROWS 4096   // B*T

__device__ __forceinline__ void load_lds16(const bf16* g, bf16* l) {
  __builtin_amdgcn_global_load_lds(
      (const __attribute__((address_space(1))) unsigned int*)g,
      (__attribute__((address_space(3))) unsigned int*)l, 16, 0, 0);
}

__device__ __forceinline__ float b2f(short s) {
  unsigned int u = ((unsigned int)(unsigned short)s) << 16;
  return __builtin_bit_cast(float, u);
}

// pack two f32 -> two bf16 (RNE), single instruction; dst.lo = a, dst.hi = b
__device__ __forceinline__ unsigned cvtpk(float a, float b) {
  unsigned r;
  asm("v_cvt_pk_bf16_f32 %0, %1, %2" : "=v"(r) : "v"(a), "v"(b));
  return r;
}

// v_permlane32_swap_b32 vdst, src: vdst[32:63] <-> src[0:31]
// (vdst lanes 0-31 and src lanes 32-63 unchanged)
__device__ __forceinline__ void pl32swap(unsigned &d, unsigned &s) {
  asm("v_permlane32_swap_b32 %0, %1" : "+v"(d), "+v"(s));
}

// tanh-approx GELU via hw exp; |err| < ~1e-3 (vs exact-erf reference)
__device__ __forceinline__ float gelu_f(float x) {
  float u = 0.7978845608028654f * fmaf(0.044715f * x, x * x, x);
  float e = __expf(2.0f * u);
  float t = 1.0f - 2.0f / (e + 1.0f);   // tanh(u)
  return 0.5f * x * (1.0f + t);
}

// ---------------- LayerNorm (fp32 in) -> bf16 out ----------------
__global__ __launch_bounds__(256)
void ln_cast_kernel(const float* __restrict__ x, const float* __restrict__ g,
                    const float* __restrict__ b, bf16* __restrict__ out) {
  int row = blockIdx.x, tid = threadIdx.x;
  const float4 v = ((const float4*)(x + (size_t)row * NC))[tid];
  float s  = v.x + v.y + v.z + v.w;
  float s2 = v.x*v.x + v.y*v.y + v.z*v.z + v.w*v.w;
#pragma unroll
  for (int m = 1; m < 64; m <<= 1) { s += __shfl_xor(s, m); s2 += __shfl_xor(s2, m); }
  __shared__ float rs[4], rs2[4];
  if ((tid & 63) == 0) { rs[tid >> 6] = s; rs2[tid >> 6] = s2; }
  __syncthreads();
  s  = rs[0] + rs[1] + rs[2] + rs[3];
  s2 = rs2[0] + rs2[1] + rs2[2] + rs2[3];
  float mu   = s * (1.0f / NC);
  float var  = s2 * (1.0f / NC) - mu * mu;
  float rstd = rsqrtf(var + 1e-5f);
  const float4 gv = ((const float4*)g)[tid];
  const float4 bv = ((const float4*)b)[tid];
  bf16* o = out + (size_t)row * NC + tid * 4;
  o[0] = __float2bfloat16((v.x - mu) * rstd * gv.x + bv.x);
  o[1] = __float2bfloat16((v.y - mu) * rstd * gv.y + bv.y);
  o[2] = __float2bfloat16((v.z - mu) * rstd * gv.z + bv.z);
  o[3] = __float2bfloat16((v.w - mu) * rstd * gv.w + bv.w);
}

// ---- x2 = x + bo + P0 + P1 (bf16 partials); then LN(x2) -> xn2 (fused) ----
__global__ __launch_bounds__(256)
void wo_ln_kernel(const float* __restrict__ x, const float* __restrict__ bo,
                  const bf16* __restrict__ P, const float* __restrict__ g,
                  const float* __restrict__ bln, float* __restrict__ x2,
                  bf16* __restrict__ xn2) {
  int row = blockIdx.x, tid = threadIdx.x;
  size_t base = (size_t)row * NC + tid * 4;
  const float4 xv = *(const float4*)(x + base);
  const float4 bv = ((const float4*)bo)[tid];
  short4 p0 = *(const short4*)((const short*)P + base);
  short4 p1 = *(const short4*)((const short*)P + (size_t)NROWS * NC + base);
  float v0 = xv.x + bv.x + b2f(p0.x) + b2f(p1.x);
  float v1 = xv.y + bv.y + b2f(p0.y) + b2f(p1.y);
  float v2 = xv.z + bv.z + b2f(p0.z) + b2f(p1.z);
  float v3 = xv.w + bv.w + b2f(p0.w) + b2f(p1.w);
  float4 ov = {v0, v1, v2, v3};
  *(float4*)(x2 + base) = ov;
  float s  = v0 + v1 + v2 + v3;
  float s2 = v0*v0 + v1*v1 + v2*v2 + v3*v3;
#pragma unroll
  for (int m = 1; m < 64; m <<= 1) { s += __shfl_xor(s, m); s2 += __shfl_xor(s2, m); }
  __shared__ float rs[4], rs2[4];
  if ((tid & 63) == 0) { rs[tid >> 6] = s; rs2[tid >> 6] = s2; }
  __syncthreads();
  s  = rs[0] + rs[1] + rs[2] + rs[3];
  s2 = rs2[0] + rs2[1] + rs2[2] + rs2[3];
  float mu   = s * (1.0f / NC);
  float var  = s2 * (1.0f / NC) - mu * mu;
  float rstd = rsqrtf(var + 1e-5f);
  const float4 gv = ((const float4*)g)[tid];
  const float4 lv = ((const float4*)bln)[tid];
  bf16* o = xn2 + base;
  o[0] = __float2bfloat16((v0 - mu) * rstd * gv.x + lv.x);
  o[1] = __float2bfloat16((v1 - mu) * rstd * gv.y + lv.y);
  o[2] = __float2bfloat16((v2 - mu) * rstd * gv.z + lv.z);
  o[3] = __float2bfloat16((v3 - mu) * rstd * gv.w + lv.w);
}

// ---- d_out = x2 + b2 + sum of 4 bf16 partials ----
__global__ __launch_bounds__(256)
void w2_final_kernel(const float* __restrict__ x2, const float* __restrict__ b2,
                     const bf16* __restrict__ P, float* __restrict__ out) {
  int row = blockIdx.x, tid = threadIdx.x;
  size_t base = (size_t)row * NC + tid * 4;
  const float4 xv = *(const float4*)(x2 + base);
  const float4 bv = ((const float4*)b2)[tid];
  float a0 = xv.x + bv.x, a1 = xv.y + bv.y, a2 = xv.z + bv.z, a3 = xv.w + bv.w;
#pragma unroll
  for (int z = 0; z < 4; ++z) {
    short4 p = *(const short4*)((const short*)P + (size_t)z * NROWS * NC + base);
    a0 += b2f(p.x); a1 += b2f(p.y); a2 += b2f(p.z); a3 += b2f(p.w);
  }
  float4 ov = {a0, a1, a2, a3};
  *(float4*)(out + base) = ov;
}

// ---------------- all weight transposes in one launch ----------------
__global__ __launch_bounds__(256)
void transpose_all_kernel(const float* __restrict__ Wq, const float* __restrict__ Wk,
                          const float* __restrict__ Wv, const float* __restrict__ Wo,
                          const float* __restrict__ W1, const float* __restrict__ W2,
                          bf16* __restrict__ WqkvoT, bf16* __restrict__ W1T,
                          bf16* __restrict__ W2T) {
  int bid = blockIdx.x;
  const float* W; bf16* Wt; int K, N, nx, tile;
  if (bid < 4096) {
    int z = bid >> 10; tile = bid & 1023;
    W = (z == 0) ? Wq : (z == 1) ? Wk : (z == 2) ? Wv : Wo;
    Wt = WqkvoT + (size_t)z * NC * NC; K = NC; N = NC; nx = 32;
  } else if (bid < 8192) {
    tile = bid - 4096; W = W1; Wt = W1T; K = NC; N = DFF; nx = 128;
  } else {
    tile = bid - 8192; W = W2; Wt = W2T; K = DFF; N = NC; nx = 32;
  }
  int n0 = (tile % nx) * 32, k0 = (tile / nx) * 32;
  __shared__ float t[32][33];
  int tx = threadIdx.x, ty = threadIdx.y;  // 32 x 8
#pragma unroll
  for (int i = 0; i < 4; ++i)
    t[ty + i * 8][tx] = W[(size_t)(k0 + ty + i * 8) * N + n0 + tx];
  __syncthreads();
#pragma unroll
  for (int i = 0; i < 4; ++i)
    Wt[(size_t)(n0 + ty + i * 8) * K + k0 + tx] = __float2bfloat16(t[tx][ty + i * 8]);
}

// ---------------- GEMM v2: 32x32x16 MFMA, BK=64, xor-swizzled LDS ----------------
// C(MxN) = A(MxK,bf16) @ Bt(NxK,bf16)^T. Block 128x128, wave 64x64 (2x2 of 32x32).
#define MODE_GELU 4
#define MODE_QKV  5
#define MODE_PART 6

template <int MODE>
__global__ __launch_bounds__(256)
void gemm_bt(const bf16* __restrict__ A, const bf16* __restrict__ Bt,
             const float* __restrict__ bias, const float* __restrict__ bias2,
             const float* __restrict__ bias3,
             void* __restrict__ outp, void* __restrict__ out2, void* __restrict__ out3,
             int M, int N, int K, int KS) {
  __shared__ bf16 As[128 * 64];
  __shared__ bf16 Bs[128 * 64];
  int tid  = threadIdx.x;
  int w    = tid >> 6;
  int lane = tid & 63;
  int l32  = lane & 31;
  int khalf = lane >> 5;          // which K-half of the fragment this lane holds
  int sx   = lane & 7;            // xor key for swizzled frag reads (== row&7)
  int waveM = (w >> 1) * 64, waveN = (w & 1) * 64;

  // L2 block swizzle (GROUP_M = 8)
  int gN = gridDim.x, gM = gridDim.y;
  int pid = blockIdx.y * gN + blockIdx.x;
  int npg = 8 * gN;
  int gid = pid / npg;
  int fm  = gid * 8;
  int gsz = min(gM - fm, 8);
  int bm = (fm + (pid % gsz)) * 128;
  int bn = ((pid % npg) / gsz) * 128;

  int k_beg = blockIdx.z * KS;

  const bf16* pA[4]; const bf16* pB[4];
#pragma unroll
  for (int i = 0; i < 4; ++i) {
    int p = i * 256 + tid;
    int row = p >> 3;
    int lc = (p & 7) ^ (row & 7);
    pA[i] = A  + (size_t)(bm + row) * K + k_beg + lc * 8;
    pB[i] = Bt + (size_t)(bn + row) * K + k_beg + lc * 8;
  }

  f32x16 acc[2][2];
#pragma unroll
  for (int mi = 0; mi < 2; ++mi)
#pragma unroll
    for (int ni = 0; ni < 2; ++ni)
#pragma unroll
      for (int r = 0; r < 16; ++r) acc[mi][ni][r] = 0.f;

  for (int kt = 0; kt < KS; kt += 64) {
    __syncthreads();
#pragma unroll
    for (int i = 0; i < 4; ++i) {
      load_lds16(pA[i], &As[(i * 256 + w * 64) * 8]);
      load_lds16(pB[i], &Bs[(i * 256 + w * 64) * 8]);
      pA[i] += 64; pB[i] += 64;
    }
    __syncthreads();
#pragma unroll
    for (int s = 0; s < 4; ++s) {          // k-step of 16
      int ch = ((s * 2 + khalf) ^ sx) * 8;
      bf16x8 af[2], bfr[2];
#pragma unroll
      for (int mi = 0; mi < 2; ++mi)
        af[mi] = *(const bf16x8*)&As[(waveM + mi * 32 + l32) * 64 + ch];
#pragma unroll
      for (int ni = 0; ni < 2; ++ni)
        bfr[ni] = *(const bf16x8*)&Bs[(waveN + ni * 32 + l32) * 64 + ch];
#pragma unroll
      for (int mi = 0; mi < 2; ++mi)
#pragma unroll
        for (int ni = 0; ni < 2; ++ni)
          acc[mi][ni] = __builtin_amdgcn_mfma_f32_32x32x16_bf16(af[mi], bfr[ni], acc[mi][ni], 0, 0, 0);
    }
  }

  // ---- epilogues (C layout: col = l32, row = (reg&3) + 8*(reg>>2) + 4*khalf) ----
  if (MODE == MODE_PART) {
    bf16* dst = (bf16*)outp + (size_t)blockIdx.z * M * N;
#pragma unroll
    for (int mi = 0; mi < 2; ++mi)
#pragma unroll
      for (int ni = 0; ni < 2; ++ni) {
        int col = bn + waveN + ni * 32 + l32;
#pragma unroll
        for (int reg = 0; reg < 16; ++reg) {
          int row = bm + waveM + mi * 32 + (reg & 3) + 8 * (reg >> 2) + 4 * khalf;
          dst[(size_t)row * N + col] = __float2bfloat16(acc[mi][ni][reg]);
        }
      }
  } else if (MODE == MODE_GELU) {
    float bcol[2];
#pragma unroll
    for (int ni = 0; ni < 2; ++ni) bcol[ni] = bias[bn + waveN + ni * 32 + l32];
#pragma unroll
    for (int mi = 0; mi < 2; ++mi)
#pragma unroll
      for (int ni = 0; ni < 2; ++ni) {
        int col = bn + waveN + ni * 32 + l32;
#pragma unroll
        for (int reg = 0; reg < 16; ++reg) {
          int row = bm + waveM + mi * 32 + (reg & 3) + 8 * (reg >> 2) + 4 * khalf;
          ((bf16*)outp)[(size_t)row * N + col] =
              __float2bfloat16(gelu_f(acc[mi][ni][reg] + bcol[ni]));
        }
      }
  } else {  // MODE_QKV: seg block-uniform
    int seg = bn >> 10;
    int c1b = (bn & (NC - 1)) + waveN;
    const float* bp = (seg == 0) ? bias : (seg == 1) ? bias2 : bias3;
    float bcol[2]; int hh[2], dd[2];
#pragma unroll
    for (int ni = 0; ni < 2; ++ni) {
      int c1 = c1b + ni * 32 + l32;
      bcol[ni] = bp[c1]; hh[ni] = c1 >> 6; dd[ni] = c1 & (HD - 1);
    }
    if (seg < 2) {
      bf16* dst = (seg == 0) ? (bf16*)outp : (bf16*)out2;
#pragma unroll
      for (int mi = 0; mi < 2; ++mi)
#pragma unroll
        for (int reg = 0; reg < 16; ++reg) {
          int row = bm + waveM + mi * 32 + (reg & 3) + 8 * (reg >> 2) + 4 * khalf;
          int bbi = row >> 11, t = row & (TSEQ - 1);
#pragma unroll
          for (int ni = 0; ni < 2; ++ni)
            dst[((size_t)(bbi * NH + hh[ni]) * TSEQ + t) * HD + dd[ni]] =
                __float2bfloat16(acc[mi][ni][reg] + bcol[ni]);
        }
    } else {
      bf16* dst = (bf16*)out3;
#pragma unroll
      for (int mi = 0; mi < 2; ++mi)
#pragma unroll
        for (int reg = 0; reg < 16; ++reg) {
          int row = bm + waveM + mi * 32 + (reg & 3) + 8 * (reg >> 2) + 4 * khalf;
          int bbi = row >> 11, t = row & (TSEQ - 1);
#pragma unroll
          for (int ni = 0; ni < 2; ++ni)
            dst[((size_t)(bbi * NH + hh[ni]) * HD + dd[ni]) * TSEQ + t] =
                __float2bfloat16(acc[mi][ni][reg] + bcol[ni]);
        }
    }
  }
}

// ---------------- Flash attention v4.1: swapped-QK^T 32x32, no LDS ----------------
// One wave per 32-row q-tile. S^T = mfma(K_frag, Q_frag) puts q lane-local
// (C: col=lane&31=q, row=(reg&3)+8*(reg>>2)+4*(lane>>5)=key), so softmax sum is
// per-lane; P->A-frag for PV via 8 cvt_pk + 4 permlane32_swap (HK pairing:
// swap(pk(p0,p1), pk(p4,p5)) -> {word0, word2}; vdst_hi <-> src_lo semantics).
// K/Q/V fragments are contiguous 16B global loads (K/V per head = 512KB,
// L2-resident: no LDS, no barriers). Block decode: 4 heads per XCD; per-CU
// wave-length pairing (2c+1)+(64-2c)=65 keeps CU work uniform.
__global__ __launch_bounds__(64)
void attn_kernel(const bf16* __restrict__ q, const bf16* __restrict__ k,
                 const bf16* __restrict__ vT, bf16* __restrict__ out) {
  int id   = blockIdx.x;           // 0..2047
  int xcd  = id & 7;
  int slot = id >> 3;              // 0..255
  int bh   = xcd * 4 + (slot >> 6);
  int s64  = slot & 63;
  int qt   = (s64 < 32) ? (2 * s64) : (63 - 2 * (s64 - 32));
  int b = bh >> 4, h = bh & 15;

  int lane = threadIdx.x;
  int l31  = lane & 31;
  int hh   = lane >> 5;            // 0/1
  int h8   = hh * 8;
  int base4 = hh * 4;

  const bf16* qp = q  + (size_t)(b * NH + h) * TSEQ * HD;
  const bf16* kp = k  + (size_t)(b * NH + h) * TSEQ * HD;
  const bf16* vp = vT + (size_t)(b * NH + h) * HD * TSEQ;

  int q0 = qt * 32;

  // Q fragments (B-operand): lane holds Q[q0+l31][ds*16 + h8 .. +7]
  bf16x8 qf[4];
#pragma unroll
  for (int ds = 0; ds < 4; ++ds)
    qf[ds] = *(const bf16x8*)(qp + (size_t)(q0 + l31) * HD + ds * 16 + h8);

  f32x16 o0, o1;
#pragma unroll
  for (int r = 0; r < 16; ++r) { o0[r] = 0.f; o1[r] = 0.f; }
  float lacc = 0.f;

  const bf16* kb = kp + (size_t)l31 * HD + h8;     // + kt*32*HD + ds*16
  const bf16* vb = vp + (size_t)l31 * TSEQ + h8;   // + dt*32*TSEQ + k0 + ks*16

  // K fragments (A-operand) for kt=0, double-buffered across steps
  bf16x8 a0 = *(const bf16x8*)(kb);
  bf16x8 a1 = *(const bf16x8*)(kb + 16);
  bf16x8 a2 = *(const bf16x8*)(kb + 32);
  bf16x8 a3 = *(const bf16x8*)(kb + 48);

  auto step = [&](int kt, bool dg) {
    int k0 = kt * 32;
    // V fragments (B-operand): vT[dt*32+l31][k0 + ks*16 + h8 .. +7]
    bf16x8 v00 = *(const bf16x8*)(vb + k0);
    bf16x8 v01 = *(const bf16x8*)(vb + k0 + 16);
    bf16x8 v10 = *(const bf16x8*)(vb + (size_t)32 * TSEQ + k0);
    bf16x8 v11 = *(const bf16x8*)(vb + (size_t)32 * TSEQ + k0 + 16);
    // prefetch next K tile (hidden under QK + softmax)
    bf16x8 n0, n1, n2, n3;
    if (!dg) {
      const bf16* kn = kb + (size_t)(k0 + 32) * HD;
      n0 = *(const bf16x8*)(kn);
      n1 = *(const bf16x8*)(kn + 16);
      n2 = *(const bf16x8*)(kn + 32);
      n3 = *(const bf16x8*)(kn + 48);
    }

    f32x16 c;
#pragma unroll
    for (int r = 0; r < 16; ++r) c[r] = 0.f;
    c = __builtin_amdgcn_mfma_f32_32x32x16_bf16(a0, qf[0], c, 0, 0, 0);
    c = __builtin_amdgcn_mfma_f32_32x32x16_bf16(a1, qf[1], c, 0, 0, 0);
    c = __builtin_amdgcn_mfma_f32_32x32x16_bf16(a2, qf[2], c, 0, 0, 0);
    c = __builtin_amdgcn_mfma_f32_32x32x16_bf16(a3, qf[3], c, 0, 0, 0);

    // softmax: p = exp(S/8 - 8) = exp2(S*0.125*log2e - 8*log2e); q is lane-local
    float p[16];
    float ls = 0.f;
#pragma unroll
    for (int r = 0; r < 16; ++r) {
      float pv = exp2f(fmaf(c[r], 0.18033688011112042f, -11.541560327111707f));
      if (dg) {
        int krr = (r & 3) + 8 * (r >> 2) + base4;
        pv = (krr <= l31) ? pv : 0.f;
      }
      p[r] = pv;
      ls += pv;
    }
    lacc += ls;

    // P (f32, key=kr(r,hh)) -> PV A-fragments.
    // swap(vdst=pk(p0,p1), src=pk(p4,p5)): new-vdst = frag word0, new-src = word2
    // (vdst_hi <-> src_lo). Same pattern for words 1/3 and the second chunk.
    unsigned A0 = cvtpk(p[0],  p[1]),  C0 = cvtpk(p[4],  p[5]);
    unsigned B0 = cvtpk(p[2],  p[3]),  D0 = cvtpk(p[6],  p[7]);
    pl32swap(A0, C0); pl32swap(B0, D0);
    unsigned A1 = cvtpk(p[8],  p[9]),  C1 = cvtpk(p[12], p[13]);
    unsigned B1 = cvtpk(p[10], p[11]), D1 = cvtpk(p[14], p[15]);
    pl32swap(A1, C1); pl32swap(B1, D1);
    u32x4 w0 = {A0, B0, C0, D0};
    u32x4 w1 = {A1, B1, C1, D1};
    bf16x8 pa0 = __builtin_bit_cast(bf16x8, w0);
    bf16x8 pa1 = __builtin_bit_cast(bf16x8, w1);

    o0 = __builtin_amdgcn_mfma_f32_32x32x16_bf16(pa0, v00, o0, 0, 0, 0);
    o0 = __builtin_amdgcn_mfma_f32_32x32x16_bf16(pa1, v01, o0, 0, 0, 0);
    o1 = __builtin_amdgcn_mfma_f32_32x32x16_bf16(pa0, v10, o1, 0, 0, 0);
    o1 = __builtin_amdgcn_mfma_f32_32x32x16_bf16(pa1, v11, o1, 0, 0, 0);

    if (!dg) { a0 = n0; a1 = n1; a2 = n2; a3 = n3; }
  };

  for (int kt = 0; kt < qt; ++kt) step(kt, false);
  step(qt, true);

  // normalize: lane l holds denom-half for q-row l31; combine across halves
  float ltot = lacc + __shfl_xor(lacc, 32);
  float linv = 1.0f / ltot;
#pragma unroll
  for (int r = 0; r < 16; ++r) {
    int qoff = (r & 3) + 8 * (r >> 2) + base4;
    float sc = __shfl(linv, qoff);
    size_t ob = ((size_t)(b * TSEQ + q0 + qoff)) * NC + h * HD + l31;
    out[ob]      = __float2bfloat16(o0[r] * sc);
    out[ob + 32] = __float2bfloat16(o1[r] * sc);
  }
}

extern "C" void kernel_launch(void* const* d_in, const int* in_sizes, int n_in,
                              void* d_out, int out_size, void* d_ws, size_t ws_size,
                              hipStream_t stream) {
  const float* x     = (const float*)d_in[0];
  const float* ln1_g = (const float*)d_in[1];
  const float* ln1_b = (const float*)d_in[2];
  const float* Wq    = (const float*)d_in[3];
  const float* bq    = (const float*)d_in[4];
  const float* Wk    = (const float*)d_in[5];
  const float* bk    = (const float*)d_in[6];
  const float* Wv    = (const float*)d_in[7];
  const float* bv    = (const float*)d_in[8];
  const float* Wo    = (const float*)d_in[9];
  const float* bo    = (const float*)d_in[10];
  const float* ln2_g = (const float*)d_in[11];
  const float* ln2_b = (const float*)d_in[12];
  const float* W1    = (const float*)d_in[13];
  const float* b1    = (const float*)d_in[14];
  const float* W2    = (const float*)d_in[15];
  const float* b2    = (const float*)d_in[16];

  char* ws = (char*)d_ws;
  const size_t MB = 1u << 20;
  bf16* WqkvT = (bf16*)(ws + 0 * MB);   // 4x1024x1024 (q|k|v|o)
  bf16* W1T  = (bf16*)(ws + 8 * MB);    // 4096x1024
  bf16* W2T  = (bf16*)(ws + 16 * MB);   // 1024x4096
  bf16* xn1  = (bf16*)(ws + 24 * MB);   // 4096x1024
  bf16* qb   = (bf16*)(ws + 32 * MB);   // (b,h,t,d)        [dead after attn]
  bf16* kb   = (bf16*)(ws + 40 * MB);   // (b,h,t,d)        [dead after attn]
  bf16* vTb  = (bf16*)(ws + 48 * MB);   // (b,h,d,t)        [dead after attn]
  bf16* att  = (bf16*)(ws + 56 * MB);   // 4096x1024        [dead after Wo gemm]
  float* x2  = (float*)(ws + 64 * MB);  // 4096x1024 fp32
  bf16* xn2  = (bf16*)(ws + 80 * MB);   // 4096x1024
  bf16* h1   = (bf16*)(ws + 88 * MB);   // 4096x4096        [written after woP consumed]
  bf16* woP  = (bf16*)(ws + 88 * MB);   // 2x 4096x1024 Wo partials (reuses h1 region)
  bf16* w2P  = (bf16*)(ws + 32 * MB);   // 4x 4096x1024 W2 partials (reuses q/k/v/att)
  bf16* WoT  = WqkvT + 3 * (size_t)NC * NC;

  transpose_all_kernel<<<12288, dim3(32, 8), 0, stream>>>(
      Wq, Wk, Wv, Wo, W1, W2, WqkvT, W1T, W2T);

  ln_cast_kernel<<<NROWS, 256, 0, stream>>>(x, ln1_g, ln1_b, xn1);

  gemm_bt<MODE_QKV><<<dim3(24, 32, 1), 256, 0, stream>>>(
      xn1, WqkvT, bq, bk, bv, qb, kb, vTb, NROWS, 3 * NC, NC, NC);

  attn_kernel<<<2048, 64, 0, stream>>>(qb, kb, vTb, att);

  gemm_bt<MODE_PART><<<dim3(8, 32, 2), 256, 0, stream>>>(
      att, WoT, nullptr, nullptr, nullptr, woP, nullptr, nullptr, NROWS, NC, NC, NC / 2);

  wo_ln_kernel<<<NROWS, 256, 0, stream>>>(x, bo, woP, ln2_g, ln2_b, x2, xn2);

  gemm_bt<MODE_GELU><<<dim3(32, 32, 1), 256, 0, stream>>>(
      xn2, W1T, b1, nullptr, nullptr, h1, nullptr, nullptr, NROWS, DFF, NC, NC);

  gemm_bt<MODE_PART><<<dim3(8, 32, 4), 256, 0, stream>>>(
      h1, W2T, nullptr, nullptr, nullptr, w2P, nullptr, nullptr, NROWS, NC, DFF, DFF / 4);

  w2_final_kernel<<<NROWS, 256, 0, stream>>>(x2, b2, w2P, (float*)d_out);
}

// Round 4
// 370.938 us; speedup vs baseline: 1.0044x; 1.0044x over previous
//
#include <hip/hip_runtime.h>
#include <hip/hip_bf16.h>

typedef __hip_bfloat16 bf16;
using bf16x8 = __attribute__((ext_vector_type(8))) short;
using f32x4  = __attribute__((ext_vector_type(4))) float;
using f32x16 = __attribute__((ext_vector_type(16))) float;
using u32x4  = __attribute__((ext_vector_type(4))) unsigned int;

#define TSEQ 2048
#define NH   16
#define HD   64
#define NC   1024
#define DFF  4096
#define NROWS 4096   // B*T

__device__ __forceinline__ void load_lds16(const bf16* g, bf16* l) {
  __builtin_amdgcn_global_load_lds(
      (const __attribute__((address_space(1))) unsigned int*)g,
      (__attribute__((address_space(3))) unsigned int*)l, 16, 0, 0);
}

__device__ __forceinline__ float b2f(short s) {
  unsigned int u = ((unsigned int)(unsigned short)s) << 16;
  return __builtin_bit_cast(float, u);
}

// pack two f32 -> two bf16 (RNE), single instruction; dst.lo = a, dst.hi = b
__device__ __forceinline__ unsigned cvtpk(float a, float b) {
  unsigned r;
  asm("v_cvt_pk_bf16_f32 %0, %1, %2" : "=v"(r) : "v"(a), "v"(b));
  return r;
}

// v_permlane32_swap_b32 vdst, src: vdst[32:63] <-> src[0:31]
// (vdst lanes 0-31 and src lanes 32-63 unchanged)
__device__ __forceinline__ void pl32swap(unsigned &d, unsigned &s) {
  asm("v_permlane32_swap_b32 %0, %1" : "+v"(d), "+v"(s));
}

// tanh-approx GELU via hw exp; |err| < ~1e-3 (vs exact-erf reference)
__device__ __forceinline__ float gelu_f(float x) {
  float u = 0.7978845608028654f * fmaf(0.044715f * x, x * x, x);
  float e = __expf(2.0f * u);
  float t = 1.0f - 2.0f / (e + 1.0f);   // tanh(u)
  return 0.5f * x * (1.0f + t);
}

// ---------------- LayerNorm (fp32 in) -> bf16 out ----------------
__global__ __launch_bounds__(256)
void ln_cast_kernel(const float* __restrict__ x, const float* __restrict__ g,
                    const float* __restrict__ b, bf16* __restrict__ out) {
  int row = blockIdx.x, tid = threadIdx.x;
  const float4 v = ((const float4*)(x + (size_t)row * NC))[tid];
  float s  = v.x + v.y + v.z + v.w;
  float s2 = v.x*v.x + v.y*v.y + v.z*v.z + v.w*v.w;
#pragma unroll
  for (int m = 1; m < 64; m <<= 1) { s += __shfl_xor(s, m); s2 += __shfl_xor(s2, m); }
  __shared__ float rs[4], rs2[4];
  if ((tid & 63) == 0) { rs[tid >> 6] = s; rs2[tid >> 6] = s2; }
  __syncthreads();
  s  = rs[0] + rs[1] + rs[2] + rs[3];
  s2 = rs2[0] + rs2[1] + rs2[2] + rs2[3];
  float mu   = s * (1.0f / NC);
  float var  = s2 * (1.0f / NC) - mu * mu;
  float rstd = rsqrtf(var + 1e-5f);
  const float4 gv = ((const float4*)g)[tid];
  const float4 bv = ((const float4*)b)[tid];
  bf16* o = out + (size_t)row * NC + tid * 4;
  o[0] = __float2bfloat16((v.x - mu) * rstd * gv.x + bv.x);
  o[1] = __float2bfloat16((v.y - mu) * rstd * gv.y + bv.y);
  o[2] = __float2bfloat16((v.z - mu) * rstd * gv.z + bv.z);
  o[3] = __float2bfloat16((v.w - mu) * rstd * gv.w + bv.w);
}

// ---- x2 = x + bo + P0 + P1 (bf16 partials); then LN(x2) -> xn2 (fused) ----
__global__ __launch_bounds__(256)
void wo_ln_kernel(const float* __restrict__ x, const float* __restrict__ bo,
                  const bf16* __restrict__ P, const float* __restrict__ g,
                  const float* __restrict__ bln, float* __restrict__ x2,
                  bf16* __restrict__ xn2) {
  int row = blockIdx.x, tid = threadIdx.x;
  size_t base = (size_t)row * NC + tid * 4;
  const float4 xv = *(const float4*)(x + base);
  const float4 bv = ((const float4*)bo)[tid];
  short4 p0 = *(const short4*)((const short*)P + base);
  short4 p1 = *(const short4*)((const short*)P + (size_t)NROWS * NC + base);
  float v0 = xv.x + bv.x + b2f(p0.x) + b2f(p1.x);
  float v1 = xv.y + bv.y + b2f(p0.y) + b2f(p1.y);
  float v2 = xv.z + bv.z + b2f(p0.z) + b2f(p1.z);
  float v3 = xv.w + bv.w + b2f(p0.w) + b2f(p1.w);
  float4 ov = {v0, v1, v2, v3};
  *(float4*)(x2 + base) = ov;
  float s  = v0 + v1 + v2 + v3;
  float s2 = v0*v0 + v1*v1 + v2*v2 + v3*v3;
#pragma unroll
  for (int m = 1; m < 64; m <<= 1) { s += __shfl_xor(s, m); s2 += __shfl_xor(s2, m); }
  __shared__ float rs[4], rs2[4];
  if ((tid & 63) == 0) { rs[tid >> 6] = s; rs2[tid >> 6] = s2; }
  __syncthreads();
  s  = rs[0] + rs[1] + rs[2] + rs[3];
  s2 = rs2[0] + rs2[1] + rs2[2] + rs2[3];
  float mu   = s * (1.0f / NC);
  float var  = s2 * (1.0f / NC) - mu * mu;
  float rstd = rsqrtf(var + 1e-5f);
  const float4 gv = ((const float4*)g)[tid];
  const float4 lv = ((const float4*)bln)[tid];
  bf16* o = xn2 + base;
  o[0] = __float2bfloat16((v0 - mu) * rstd * gv.x + lv.x);
  o[1] = __float2bfloat16((v1 - mu) * rstd * gv.y + lv.y);
  o[2] = __float2bfloat16((v2 - mu) * rstd * gv.z + lv.z);
  o[3] = __float2bfloat16((v3 - mu) * rstd * gv.w + lv.w);
}

// ---- d_out = x2 + b2 + sum of 4 bf16 partials ----
__global__ __launch_bounds__(256)
void w2_final_kernel(const float* __restrict__ x2, const float* __restrict__ b2,
                     const bf16* __restrict__ P, float* __restrict__ out) {
  int row = blockIdx.x, tid = threadIdx.x;
  size_t base = (size_t)row * NC + tid * 4;
  const float4 xv = *(const float4*)(x2 + base);
  const float4 bv = ((const float4*)b2)[tid];
  float a0 = xv.x + bv.x, a1 = xv.y + bv.y, a2 = xv.z + bv.z, a3 = xv.w + bv.w;
#pragma unroll
  for (int z = 0; z < 4; ++z) {
    short4 p = *(const short4*)((const short*)P + (size_t)z * NROWS * NC + base);
    a0 += b2f(p.x); a1 += b2f(p.y); a2 += b2f(p.z); a3 += b2f(p.w);
  }
  float4 ov = {a0, a1, a2, a3};
  *(float4*)(out + base) = ov;
}

// ---------------- all weight transposes in one launch ----------------
__global__ __launch_bounds__(256)
void transpose_all_kernel(const float* __restrict__ Wq, const float* __restrict__ Wk,
                          const float* __restrict__ Wv, const float* __restrict__ Wo,
                          const float* __restrict__ W1, const float* __restrict__ W2,
                          bf16* __restrict__ WqkvoT, bf16* __restrict__ W1T,
                          bf16* __restrict__ W2T) {
  int bid = blockIdx.x;
  const float* W; bf16* Wt; int K, N, nx, tile;
  if (bid < 4096) {
    int z = bid >> 10; tile = bid & 1023;
    W = (z == 0) ? Wq : (z == 1) ? Wk : (z == 2) ? Wv : Wo;
    Wt = WqkvoT + (size_t)z * NC * NC; K = NC; N = NC; nx = 32;
  } else if (bid < 8192) {
    tile = bid - 4096; W = W1; Wt = W1T; K = NC; N = DFF; nx = 128;
  } else {
    tile = bid - 8192; W = W2; Wt = W2T; K = DFF; N = NC; nx = 32;
  }
  int n0 = (tile % nx) * 32, k0 = (tile / nx) * 32;
  __shared__ float t[32][33];
  int tx = threadIdx.x, ty = threadIdx.y;  // 32 x 8
#pragma unroll
  for (int i = 0; i < 4; ++i)
    t[ty + i * 8][tx] = W[(size_t)(k0 + ty + i * 8) * N + n0 + tx];
  __syncthreads();
#pragma unroll
  for (int i = 0; i < 4; ++i)
    Wt[(size_t)(n0 + ty + i * 8) * K + k0 + tx] = __float2bfloat16(t[tx][ty + i * 8]);
}

// ---------------- GEMM v2: 32x32x16 MFMA, BK=64, xor-swizzled LDS ----------------
// C(MxN) = A(MxK,bf16) @ Bt(NxK,bf16)^T. Block 128x128, wave 64x64 (2x2 of 32x32).
#define MODE_GELU 4
#define MODE_QKV  5
#define MODE_PART 6

template <int MODE>
__global__ __launch_bounds__(256)
void gemm_bt(const bf16* __restrict__ A, const bf16* __restrict__ Bt,
             const float* __restrict__ bias, const float* __restrict__ bias2,
             const float* __restrict__ bias3,
             void* __restrict__ outp, void* __restrict__ out2, void* __restrict__ out3,
             int M, int N, int K, int KS) {
  __shared__ bf16 As[128 * 64];
  __shared__ bf16 Bs[128 * 64];
  int tid  = threadIdx.x;
  int w    = tid >> 6;
  int lane = tid & 63;
  int l32  = lane & 31;
  int khalf = lane >> 5;          // which K-half of the fragment this lane holds
  int sx   = lane & 7;            // xor key for swizzled frag reads (== row&7)
  int waveM = (w >> 1) * 64, waveN = (w & 1) * 64;

  // L2 block swizzle (GROUP_M = 8)
  int gN = gridDim.x, gM = gridDim.y;
  int pid = blockIdx.y * gN + blockIdx.x;
  int npg = 8 * gN;
  int gid = pid / npg;
  int fm  = gid * 8;
  int gsz = min(gM - fm, 8);
  int bm = (fm + (pid % gsz)) * 128;
  int bn = ((pid % npg) / gsz) * 128;

  int k_beg = blockIdx.z * KS;

  const bf16* pA[4]; const bf16* pB[4];
#pragma unroll
  for (int i = 0; i < 4; ++i) {
    int p = i * 256 + tid;
    int row = p >> 3;
    int lc = (p & 7) ^ (row & 7);
    pA[i] = A  + (size_t)(bm + row) * K + k_beg + lc * 8;
    pB[i] = Bt + (size_t)(bn + row) * K + k_beg + lc * 8;
  }

  f32x16 acc[2][2];
#pragma unroll
  for (int mi = 0; mi < 2; ++mi)
#pragma unroll
    for (int ni = 0; ni < 2; ++ni)
#pragma unroll
      for (int r = 0; r < 16; ++r) acc[mi][ni][r] = 0.f;

  for (int kt = 0; kt < KS; kt += 64) {
    __syncthreads();
#pragma unroll
    for (int i = 0; i < 4; ++i) {
      load_lds16(pA[i], &As[(i * 256 + w * 64) * 8]);
      load_lds16(pB[i], &Bs[(i * 256 + w * 64) * 8]);
      pA[i] += 64; pB[i] += 64;
    }
    __syncthreads();
#pragma unroll
    for (int s = 0; s < 4; ++s) {          // k-step of 16
      int ch = ((s * 2 + khalf) ^ sx) * 8;
      bf16x8 af[2], bfr[2];
#pragma unroll
      for (int mi = 0; mi < 2; ++mi)
        af[mi] = *(const bf16x8*)&As[(waveM + mi * 32 + l32) * 64 + ch];
#pragma unroll
      for (int ni = 0; ni < 2; ++ni)
        bfr[ni] = *(const bf16x8*)&Bs[(waveN + ni * 32 + l32) * 64 + ch];
#pragma unroll
      for (int mi = 0; mi < 2; ++mi)
#pragma unroll
        for (int ni = 0; ni < 2; ++ni)
          acc[mi][ni] = __builtin_amdgcn_mfma_f32_32x32x16_bf16(af[mi], bfr[ni], acc[mi][ni], 0, 0, 0);
    }
  }

  // ---- epilogues (C layout: col = l32, row = (reg&3) + 8*(reg>>2) + 4*khalf) ----
  if (MODE == MODE_PART) {
    bf16* dst = (bf16*)outp + (size_t)blockIdx.z * M * N;
#pragma unroll
    for (int mi = 0; mi < 2; ++mi)
#pragma unroll
      for (int ni = 0; ni < 2; ++ni) {
        int col = bn + waveN + ni * 32 + l32;
#pragma unroll
        for (int reg = 0; reg < 16; ++reg) {
          int row = bm + waveM + mi * 32 + (reg & 3) + 8 * (reg >> 2) + 4 * khalf;
          dst[(size_t)row * N + col] = __float2bfloat16(acc[mi][ni][reg]);
        }
      }
  } else if (MODE == MODE_GELU) {
    float bcol[2];
#pragma unroll
    for (int ni = 0; ni < 2; ++ni) bcol[ni] = bias[bn + waveN + ni * 32 + l32];
#pragma unroll
    for (int mi = 0; mi < 2; ++mi)
#pragma unroll
      for (int ni = 0; ni < 2; ++ni) {
        int col = bn + waveN + ni * 32 + l32;
#pragma unroll
        for (int reg = 0; reg < 16; ++reg) {
          int row = bm + waveM + mi * 32 + (reg & 3) + 8 * (reg >> 2) + 4 * khalf;
          ((bf16*)outp)[(size_t)row * N + col] =
              __float2bfloat16(gelu_f(acc[mi][ni][reg] + bcol[ni]));
        }
      }
  } else {  // MODE_QKV: seg block-uniform
    int seg = bn >> 10;
    int c1b = (bn & (NC - 1)) + waveN;
    const float* bp = (seg == 0) ? bias : (seg == 1) ? bias2 : bias3;
    float bcol[2]; int hh[2], dd[2];
#pragma unroll
    for (int ni = 0; ni < 2; ++ni) {
      int c1 = c1b + ni * 32 + l32;
      bcol[ni] = bp[c1]; hh[ni] = c1 >> 6; dd[ni] = c1 & (HD - 1);
    }
    if (seg < 2) {
      bf16* dst = (seg == 0) ? (bf16*)outp : (bf16*)out2;
#pragma unroll
      for (int mi = 0; mi < 2; ++mi)
#pragma unroll
        for (int reg = 0; reg < 16; ++reg) {
          int row = bm + waveM + mi * 32 + (reg & 3) + 8 * (reg >> 2) + 4 * khalf;
          int bbi = row >> 11, t = row & (TSEQ - 1);
#pragma unroll
          for (int ni = 0; ni < 2; ++ni)
            dst[((size_t)(bbi * NH + hh[ni]) * TSEQ + t) * HD + dd[ni]] =
                __float2bfloat16(acc[mi][ni][reg] + bcol[ni]);
        }
    } else {
      bf16* dst = (bf16*)out3;
#pragma unroll
      for (int mi = 0; mi < 2; ++mi)
#pragma unroll
        for (int reg = 0; reg < 16; ++reg) {
          int row = bm + waveM + mi * 32 + (reg & 3) + 8 * (reg >> 2) + 4 * khalf;
          int bbi = row >> 11, t = row & (TSEQ - 1);
#pragma unroll
          for (int ni = 0; ni < 2; ++ni)
            dst[((size_t)(bbi * NH + hh[ni]) * HD + dd[ni]) * TSEQ + t] =
                __float2bfloat16(acc[mi][ni][reg] + bcol[ni]);
        }
    }
  }
}

// ---------------- Flash attention v5: swapped-QK^T 32x32, split-K x4 ----------------
// One BLOCK (4 waves) per 32-row q-tile; wave w handles key-tiles kt ≡ w (mod 4).
// Swapped S^T = mfma(K,Q) keeps q lane-local (softmax per-lane); P->A-frag via
// 8 cvt_pk + 4 permlane32_swap. K/Q/V fragments are contiguous 16B global loads
// (K/V per head = 512KB, L2-resident). Partials combined via 2-round LDS tree.
// Decode: per-XCD arrival index t; bh = t&3 (same-(b,h) per CU for L1/L2
// locality, assuming round-robin CU fill); u=t>>2 pairs tiles (2u / 63-2u) so
// each CU's blocks sum to equal work (4 pairs x 65 steps).
__global__ __launch_bounds__(256)
void attn_kernel(const bf16* __restrict__ q, const bf16* __restrict__ k,
                 const bf16* __restrict__ vT, bf16* __restrict__ out) {
  int id  = blockIdx.x;            // 0..2047
  int xcd = id & 7;
  int t   = id >> 3;               // per-XCD arrival index 0..255
  int bh  = xcd * 4 + (t & 3);
  int u   = t >> 2;                // 0..63
  int qt  = (u < 32) ? (2 * u) : (63 - 2 * (u - 32));
  int b = bh >> 4, h = bh & 15;

  int tid  = threadIdx.x;
  int w    = tid >> 6;             // split-K wave 0..3
  int lane = tid & 63;
  int l31  = lane & 31;
  int hh   = lane >> 5;            // 0/1
  int h8   = hh * 8;
  int base4 = hh * 4;

  const bf16* qp = q  + (size_t)(b * NH + h) * TSEQ * HD;
  const bf16* kp = k  + (size_t)(b * NH + h) * TSEQ * HD;
  const bf16* vp = vT + (size_t)(b * NH + h) * HD * TSEQ;

  int q0 = qt * 32;

  // Q fragments (B-operand): lane holds Q[q0+l31][ds*16 + h8 .. +7]
  bf16x8 qf[4];
#pragma unroll
  for (int ds = 0; ds < 4; ++ds)
    qf[ds] = *(const bf16x8*)(qp + (size_t)(q0 + l31) * HD + ds * 16 + h8);

  f32x16 o0, o1;
#pragma unroll
  for (int r = 0; r < 16; ++r) { o0[r] = 0.f; o1[r] = 0.f; }
  float lacc = 0.f;

  const bf16* kb = kp + (size_t)l31 * HD + h8;     // + kt*32*HD + ds*16
  const bf16* vb = vp + (size_t)l31 * TSEQ + h8;   // + dt*32*TSEQ + k0 + ks*16

  bf16x8 a0, a1, a2, a3;           // K fragments (A-operand), pipelined

  auto step = [&](int kt, bool dg) {
    int k0 = kt * 32;
    // V fragments (B-operand): vT[dt*32+l31][k0 + ks*16 + h8 .. +7]
    bf16x8 v00 = *(const bf16x8*)(vb + k0);
    bf16x8 v01 = *(const bf16x8*)(vb + k0 + 16);
    bf16x8 v10 = *(const bf16x8*)(vb + (size_t)32 * TSEQ + k0);
    bf16x8 v11 = *(const bf16x8*)(vb + (size_t)32 * TSEQ + k0 + 16);
    // prefetch K for kt+4 (hidden under QK + softmax)
    bf16x8 n0, n1, n2, n3;
    bool pf = !dg && (kt + 4 <= qt);
    if (pf) {
      const bf16* kn = kb + (size_t)(k0 + 128) * HD;
      n0 = *(const bf16x8*)(kn);
      n1 = *(const bf16x8*)(kn + 16);
      n2 = *(const bf16x8*)(kn + 32);
      n3 = *(const bf16x8*)(kn + 48);
    }

    f32x16 c;
#pragma unroll
    for (int r = 0; r < 16; ++r) c[r] = 0.f;
    c = __builtin_amdgcn_mfma_f32_32x32x16_bf16(a0, qf[0], c, 0, 0, 0);
    c = __builtin_amdgcn_mfma_f32_32x32x16_bf16(a1, qf[1], c, 0, 0, 0);
    c = __builtin_amdgcn_mfma_f32_32x32x16_bf16(a2, qf[2], c, 0, 0, 0);
    c = __builtin_amdgcn_mfma_f32_32x32x16_bf16(a3, qf[3], c, 0, 0, 0);

    // softmax: p = exp(S/8 - 8) = exp2(S*0.125*log2e - 8*log2e); q is lane-local
    float p[16];
    float ls = 0.f;
#pragma unroll
    for (int r = 0; r < 16; ++r) {
      float pv = exp2f(fmaf(c[r], 0.18033688011112042f, -11.541560327111707f));
      if (dg) {
        int krr = (r & 3) + 8 * (r >> 2) + base4;
        pv = (krr <= l31) ? pv : 0.f;
      }
      p[r] = pv;
      ls += pv;
    }
    lacc += ls;

    // P (f32, key=kr(r,hh)) -> PV A-fragments.
    // swap(vdst=pk(p0,p1), src=pk(p4,p5)): new-vdst = frag word0, new-src = word2
    // (vdst_hi <-> src_lo). Same pattern for words 1/3 and the second chunk.
    unsigned A0 = cvtpk(p[0],  p[1]),  C0 = cvtpk(p[4],  p[5]);
    unsigned B0 = cvtpk(p[2],  p[3]),  D0 = cvtpk(p[6],  p[7]);
    pl32swap(A0, C0); pl32swap(B0, D0);
    unsigned A1 = cvtpk(p[8],  p[9]),  C1 = cvtpk(p[12], p[13]);
    unsigned B1 = cvtpk(p[10], p[11]), D1 = cvtpk(p[14], p[15]);
    pl32swap(A1, C1); pl32swap(B1, D1);
    u32x4 w0v = {A0, B0, C0, D0};
    u32x4 w1v = {A1, B1, C1, D1};
    bf16x8 pa0 = __builtin_bit_cast(bf16x8, w0v);
    bf16x8 pa1 = __builtin_bit_cast(bf16x8, w1v);

    o0 = __builtin_amdgcn_mfma_f32_32x32x16_bf16(pa0, v00, o0, 0, 0, 0);
    o0 = __builtin_amdgcn_mfma_f32_32x32x16_bf16(pa1, v01, o0, 0, 0, 0);
    o1 = __builtin_amdgcn_mfma_f32_32x32x16_bf16(pa0, v10, o1, 0, 0, 0);
    o1 = __builtin_amdgcn_mfma_f32_32x32x16_bf16(pa1, v11, o1, 0, 0, 0);

    if (pf) { a0 = n0; a1 = n1; a2 = n2; a3 = n3; }
  };

  if (w <= qt) {
    const bf16* ka = kb + (size_t)w * 32 * HD;
    a0 = *(const bf16x8*)(ka);
    a1 = *(const bf16x8*)(ka + 16);
    a2 = *(const bf16x8*)(ka + 32);
    a3 = *(const bf16x8*)(ka + 48);
    int diag = (w == (qt & 3)) ? 1 : 0;   // diag implies w <= qt
    int T = ((qt - w) >> 2) + 1 - diag;   // non-diag step count
    int kt = w;
    for (int i = 0; i < T; ++i, kt += 4) step(kt, false);
    if (diag) step(qt, true);
  }

  // ---- cross-wave combine: 2-round LDS tree (33-float stride: conflict-free) ----
  __shared__ float red[2][64][33];
  auto dump = [&](int slot) {
    float* d = &red[slot][lane][0];
#pragma unroll
    for (int r = 0; r < 16; ++r) { d[r] = o0[r]; d[16 + r] = o1[r]; }
    d[32] = lacc;
  };
  auto gather = [&](int slot) {
    const float* s = &red[slot][lane][0];
#pragma unroll
    for (int r = 0; r < 16; ++r) { o0[r] += s[r]; o1[r] += s[16 + r]; }
    lacc += s[32];
  };
  if (w >= 2) dump(w - 2);
  __syncthreads();
  if (w < 2) gather(w);
  __syncthreads();
  if (w == 1) dump(0);
  __syncthreads();
  if (w == 0) {
    gather(0);
    // normalize: lane l holds denom-half for q-row l31; combine across halves
    float ltot = lacc + __shfl_xor(lacc, 32);
    float linv = 1.0f / ltot;
#pragma unroll
    for (int r = 0; r < 16; ++r) {
      int qoff = (r & 3) + 8 * (r >> 2) + base4;
      float sc = __shfl(linv, qoff);
      size_t ob = ((size_t)(b * TSEQ + q0 + qoff)) * NC + h * HD + l31;
      out[ob]      = __float2bfloat16(o0[r] * sc);
      out[ob + 32] = __float2bfloat16(o1[r] * sc);
    }
  }
}

extern "C" void kernel_launch(void* const* d_in, const int* in_sizes, int n_in,
                              void* d_out, int out_size, void* d_ws, size_t ws_size,
                              hipStream_t stream) {
  const float* x     = (const float*)d_in[0];
  const float* ln1_g = (const float*)d_in[1];
  const float* ln1_b = (const float*)d_in[2];
  const float* Wq    = (const float*)d_in[3];
  const float* bq    = (const float*)d_in[4];
  const float* Wk    = (const float*)d_in[5];
  const float* bk    = (const float*)d_in[6];
  const float* Wv    = (const float*)d_in[7];
  const float* bv    = (const float*)d_in[8];
  const float* Wo    = (const float*)d_in[9];
  const float* bo    = (const float*)d_in[10];
  const float* ln2_g = (const float*)d_in[11];
  const float* ln2_b = (const float*)d_in[12];
  const float* W1    = (const float*)d_in[13];
  const float* b1    = (const float*)d_in[14];
  const float* W2    = (const float*)d_in[15];
  const float* b2    = (const float*)d_in[16];

  char* ws = (char*)d_ws;
  const size_t MB = 1u << 20;
  bf16* WqkvT = (bf16*)(ws + 0 * MB);   // 4x1024x1024 (q|k|v|o)
  bf16* W1T  = (bf16*)(ws + 8 * MB);    // 4096x1024
  bf16* W2T  = (bf16*)(ws + 16 * MB);   // 1024x4096
  bf16* xn1  = (bf16*)(ws + 24 * MB);   // 4096x1024
  bf16* qb   = (bf16*)(ws + 32 * MB);   // (b,h,t,d)        [dead after attn]
  bf16* kb   = (bf16*)(ws + 40 * MB);   // (b,h,t,d)        [dead after attn]
  bf16* vTb  = (bf16*)(ws + 48 * MB);   // (b,h,d,t)        [dead after attn]
  bf16* att  = (bf16*)(ws + 56 * MB);   // 4096x1024        [dead after Wo gemm]
  float* x2  = (float*)(ws + 64 * MB);  // 4096x1024 fp32
  bf16* xn2  = (bf16*)(ws + 80 * MB);   // 4096x1024
  bf16* h1   = (bf16*)(ws + 88 * MB);   // 4096x4096        [written after woP consumed]
  bf16* woP  = (bf16*)(ws + 88 * MB);   // 2x 4096x1024 Wo partials (reuses h1 region)
  bf16* w2P  = (bf16*)(ws + 32 * MB);   // 4x 4096x1024 W2 partials (reuses q/k/v/att)
  bf16* WoT  = WqkvT + 3 * (size_t)NC * NC;

  transpose_all_kernel<<<12288, dim3(32, 8), 0, stream>>>(
      Wq, Wk, Wv, Wo, W1, W2, WqkvT, W1T, W2T);

  ln_cast_kernel<<<NROWS, 256, 0, stream>>>(x, ln1_g, ln1_b, xn1);

  gemm_bt<MODE_QKV><<<dim3(24, 32, 1), 256, 0, stream>>>(
      xn1, WqkvT, bq, bk, bv, qb, kb, vTb, NROWS, 3 * NC, NC, NC);

  attn_kernel<<<2048, 256, 0, stream>>>(qb, kb, vTb, att);

  gemm_bt<MODE_PART><<<dim3(8, 32, 2), 256, 0, stream>>>(
      att, WoT, nullptr, nullptr, nullptr, woP, nullptr, nullptr, NROWS, NC, NC, NC / 2);

  wo_ln_kernel<<<NROWS, 256, 0, stream>>>(x, bo, woP, ln2_g, ln2_b, x2, xn2);

  gemm_bt<MODE_GELU><<<dim3(32, 32, 1), 256, 0, stream>>>(
      xn2, W1T, b1, nullptr, nullptr, h1, nullptr, nullptr, NROWS, DFF, NC, NC);

  gemm_bt<MODE_PART><<<dim3(8, 32, 4), 256, 0, stream>>>(
      h1, W2T, nullptr, nullptr, nullptr, w2P, nullptr, nullptr, NROWS, NC, DFF, DFF / 4);

  w2_final_kernel<<<NROWS, 256, 0, stream>>>(x2, b2, w2P, (float*)d_out);
}

// Round 5
// 340.455 us; speedup vs baseline: 1.0943x; 1.0895x over previous
//
#include <hip/hip_runtime.h>
#include <hip/hip_bf16.h>

typedef __hip_bfloat16 bf16;
using bf16x8 = __attribute__((ext_vector_type(8))) short;
using f32x4  = __attribute__((ext_vector_type(4))) float;
using f32x16 = __attribute__((ext_vector_type(16))) float;
using u32x4  = __attribute__((ext_vector_type(4))) unsigned int;

#define TSEQ 2048
#define NH   16
#define HD   64
#define NC   1024
#define DFF  4096
#define NROWS 4096   // B*T

__device__ __forceinline__ void load_lds16(const bf16* g, bf16* l) {
  __builtin_amdgcn_global_load_lds(
      (const __attribute__((address_space(1))) unsigned int*)g,
      (__attribute__((address_space(3))) unsigned int*)l, 16, 0, 0);
}

__device__ __forceinline__ float b2f(short s) {
  unsigned int u = ((unsigned int)(unsigned short)s) << 16;
  return __builtin_bit_cast(float, u);
}

// pack two f32 -> two bf16 (RNE), single instruction; dst.lo = a, dst.hi = b
__device__ __forceinline__ unsigned cvtpk(float a, float b) {
  unsigned r;
  asm("v_cvt_pk_bf16_f32 %0, %1, %2" : "=v"(r) : "v"(a), "v"(b));
  return r;
}

// v_permlane32_swap_b32 vdst, src: vdst[32:63] <-> src[0:31]
// (vdst lanes 0-31 and src lanes 32-63 unchanged)
__device__ __forceinline__ void pl32swap(unsigned &d, unsigned &s) {
  asm("v_permlane32_swap_b32 %0, %1" : "+v"(d), "+v"(s));
}

// tanh-approx GELU via hw exp; |err| < ~1e-3 (vs exact-erf reference)
__device__ __forceinline__ float gelu_f(float x) {
  float u = 0.7978845608028654f * fmaf(0.044715f * x, x * x, x);
  float e = __expf(2.0f * u);
  float t = 1.0f - 2.0f / (e + 1.0f);   // tanh(u)
  return 0.5f * x * (1.0f + t);
}

// ---------------- LayerNorm (fp32 in) -> bf16 out ----------------
__global__ __launch_bounds__(256)
void ln_cast_kernel(const float* __restrict__ x, const float* __restrict__ g,
                    const float* __restrict__ b, bf16* __restrict__ out) {
  int row = blockIdx.x, tid = threadIdx.x;
  const float4 v = ((const float4*)(x + (size_t)row * NC))[tid];
  float s  = v.x + v.y + v.z + v.w;
  float s2 = v.x*v.x + v.y*v.y + v.z*v.z + v.w*v.w;
#pragma unroll
  for (int m = 1; m < 64; m <<= 1) { s += __shfl_xor(s, m); s2 += __shfl_xor(s2, m); }
  __shared__ float rs[4], rs2[4];
  if ((tid & 63) == 0) { rs[tid >> 6] = s; rs2[tid >> 6] = s2; }
  __syncthreads();
  s  = rs[0] + rs[1] + rs[2] + rs[3];
  s2 = rs2[0] + rs2[1] + rs2[2] + rs2[3];
  float mu   = s * (1.0f / NC);
  float var  = s2 * (1.0f / NC) - mu * mu;
  float rstd = rsqrtf(var + 1e-5f);
  const float4 gv = ((const float4*)g)[tid];
  const float4 bv = ((const float4*)b)[tid];
  bf16* o = out + (size_t)row * NC + tid * 4;
  o[0] = __float2bfloat16((v.x - mu) * rstd * gv.x + bv.x);
  o[1] = __float2bfloat16((v.y - mu) * rstd * gv.y + bv.y);
  o[2] = __float2bfloat16((v.z - mu) * rstd * gv.z + bv.z);
  o[3] = __float2bfloat16((v.w - mu) * rstd * gv.w + bv.w);
}

// ---- x2 = x + bo + P0 + P1 (bf16 partials); then LN(x2) -> xn2 (fused) ----
__global__ __launch_bounds__(256)
void wo_ln_kernel(const float* __restrict__ x, const float* __restrict__ bo,
                  const bf16* __restrict__ P, const float* __restrict__ g,
                  const float* __restrict__ bln, float* __restrict__ x2,
                  bf16* __restrict__ xn2) {
  int row = blockIdx.x, tid = threadIdx.x;
  size_t base = (size_t)row * NC + tid * 4;
  const float4 xv = *(const float4*)(x + base);
  const float4 bv = ((const float4*)bo)[tid];
  short4 p0 = *(const short4*)((const short*)P + base);
  short4 p1 = *(const short4*)((const short*)P + (size_t)NROWS * NC + base);
  float v0 = xv.x + bv.x + b2f(p0.x) + b2f(p1.x);
  float v1 = xv.y + bv.y + b2f(p0.y) + b2f(p1.y);
  float v2 = xv.z + bv.z + b2f(p0.z) + b2f(p1.z);
  float v3 = xv.w + bv.w + b2f(p0.w) + b2f(p1.w);
  float4 ov = {v0, v1, v2, v3};
  *(float4*)(x2 + base) = ov;
  float s  = v0 + v1 + v2 + v3;
  float s2 = v0*v0 + v1*v1 + v2*v2 + v3*v3;
#pragma unroll
  for (int m = 1; m < 64; m <<= 1) { s += __shfl_xor(s, m); s2 += __shfl_xor(s2, m); }
  __shared__ float rs[4], rs2[4];
  if ((tid & 63) == 0) { rs[tid >> 6] = s; rs2[tid >> 6] = s2; }
  __syncthreads();
  s  = rs[0] + rs[1] + rs[2] + rs[3];
  s2 = rs2[0] + rs2[1] + rs2[2] + rs2[3];
  float mu   = s * (1.0f / NC);
  float var  = s2 * (1.0f / NC) - mu * mu;
  float rstd = rsqrtf(var + 1e-5f);
  const float4 gv = ((const float4*)g)[tid];
  const float4 lv = ((const float4*)bln)[tid];
  bf16* o = xn2 + base;
  o[0] = __float2bfloat16((v0 - mu) * rstd * gv.x + lv.x);
  o[1] = __float2bfloat16((v1 - mu) * rstd * gv.y + lv.y);
  o[2] = __float2bfloat16((v2 - mu) * rstd * gv.z + lv.z);
  o[3] = __float2bfloat16((v3 - mu) * rstd * gv.w + lv.w);
}

// ---- d_out = x2 + b2 + sum of 4 bf16 partials ----
__global__ __launch_bounds__(256)
void w2_final_kernel(const float* __restrict__ x2, const float* __restrict__ b2,
                     const bf16* __restrict__ P, float* __restrict__ out) {
  int row = blockIdx.x, tid = threadIdx.x;
  size_t base = (size_t)row * NC + tid * 4;
  const float4 xv = *(const float4*)(x2 + base);
  const float4 bv = ((const float4*)b2)[tid];
  float a0 = xv.x + bv.x, a1 = xv.y + bv.y, a2 = xv.z + bv.z, a3 = xv.w + bv.w;
#pragma unroll
  for (int z = 0; z < 4; ++z) {
    short4 p = *(const short4*)((const short*)P + (size_t)z * NROWS * NC + base);
    a0 += b2f(p.x); a1 += b2f(p.y); a2 += b2f(p.z); a3 += b2f(p.w);
  }
  float4 ov = {a0, a1, a2, a3};
  *(float4*)(out + base) = ov;
}

// ---------------- all weight transposes in one launch ----------------
__global__ __launch_bounds__(256)
void transpose_all_kernel(const float* __restrict__ Wq, const float* __restrict__ Wk,
                          const float* __restrict__ Wv, const float* __restrict__ Wo,
                          const float* __restrict__ W1, const float* __restrict__ W2,
                          bf16* __restrict__ WqkvoT, bf16* __restrict__ W1T,
                          bf16* __restrict__ W2T) {
  int bid = blockIdx.x;
  const float* W; bf16* Wt; int K, N, nx, tile;
  if (bid < 4096) {
    int z = bid >> 10; tile = bid & 1023;
    W = (z == 0) ? Wq : (z == 1) ? Wk : (z == 2) ? Wv : Wo;
    Wt = WqkvoT + (size_t)z * NC * NC; K = NC; N = NC; nx = 32;
  } else if (bid < 8192) {
    tile = bid - 4096; W = W1; Wt = W1T; K = NC; N = DFF; nx = 128;
  } else {
    tile = bid - 8192; W = W2; Wt = W2T; K = DFF; N = NC; nx = 32;
  }
  int n0 = (tile % nx) * 32, k0 = (tile / nx) * 32;
  __shared__ float t[32][33];
  int tx = threadIdx.x, ty = threadIdx.y;  // 32 x 8
#pragma unroll
  for (int i = 0; i < 4; ++i)
    t[ty + i * 8][tx] = W[(size_t)(k0 + ty + i * 8) * N + n0 + tx];
  __syncthreads();
#pragma unroll
  for (int i = 0; i < 4; ++i)
    Wt[(size_t)(n0 + ty + i * 8) * K + k0 + tx] = __float2bfloat16(t[tx][ty + i * 8]);
}

// ---------------- GEMM v2: 32x32x16 MFMA, BK=64, xor-swizzled LDS ----------------
// C(MxN) = A(MxK,bf16) @ Bt(NxK,bf16)^T. Block 128x128, wave 64x64 (2x2 of 32x32).
#define MODE_GELU 4
#define MODE_QKV  5
#define MODE_PART 6

template <int MODE>
__global__ __launch_bounds__(256)
void gemm_bt(const bf16* __restrict__ A, const bf16* __restrict__ Bt,
             const float* __restrict__ bias, const float* __restrict__ bias2,
             const float* __restrict__ bias3,
             void* __restrict__ outp, void* __restrict__ out2, void* __restrict__ out3,
             int M, int N, int K, int KS) {
  __shared__ bf16 As[128 * 64];
  __shared__ bf16 Bs[128 * 64];
  int tid  = threadIdx.x;
  int w    = tid >> 6;
  int lane = tid & 63;
  int l32  = lane & 31;
  int khalf = lane >> 5;          // which K-half of the fragment this lane holds
  int sx   = lane & 7;            // xor key for swizzled frag reads (== row&7)
  int waveM = (w >> 1) * 64, waveN = (w & 1) * 64;

  // L2 block swizzle (GROUP_M = 8)
  int gN = gridDim.x, gM = gridDim.y;
  int pid = blockIdx.y * gN + blockIdx.x;
  int npg = 8 * gN;
  int gid = pid / npg;
  int fm  = gid * 8;
  int gsz = min(gM - fm, 8);
  int bm = (fm + (pid % gsz)) * 128;
  int bn = ((pid % npg) / gsz) * 128;

  int k_beg = blockIdx.z * KS;

  const bf16* pA[4]; const bf16* pB[4];
#pragma unroll
  for (int i = 0; i < 4; ++i) {
    int p = i * 256 + tid;
    int row = p >> 3;
    int lc = (p & 7) ^ (row & 7);
    pA[i] = A  + (size_t)(bm + row) * K + k_beg + lc * 8;
    pB[i] = Bt + (size_t)(bn + row) * K + k_beg + lc * 8;
  }

  f32x16 acc[2][2];
#pragma unroll
  for (int mi = 0; mi < 2; ++mi)
#pragma unroll
    for (int ni = 0; ni < 2; ++ni)
#pragma unroll
      for (int r = 0; r < 16; ++r) acc[mi][ni][r] = 0.f;

  for (int kt = 0; kt < KS; kt += 64) {
    __syncthreads();
#pragma unroll
    for (int i = 0; i < 4; ++i) {
      load_lds16(pA[i], &As[(i * 256 + w * 64) * 8]);
      load_lds16(pB[i], &Bs[(i * 256 + w * 64) * 8]);
      pA[i] += 64; pB[i] += 64;
    }
    __syncthreads();
#pragma unroll
    for (int s = 0; s < 4; ++s) {          // k-step of 16
      int ch = ((s * 2 + khalf) ^ sx) * 8;
      bf16x8 af[2], bfr[2];
#pragma unroll
      for (int mi = 0; mi < 2; ++mi)
        af[mi] = *(const bf16x8*)&As[(waveM + mi * 32 + l32) * 64 + ch];
#pragma unroll
      for (int ni = 0; ni < 2; ++ni)
        bfr[ni] = *(const bf16x8*)&Bs[(waveN + ni * 32 + l32) * 64 + ch];
#pragma unroll
      for (int mi = 0; mi < 2; ++mi)
#pragma unroll
        for (int ni = 0; ni < 2; ++ni)
          acc[mi][ni] = __builtin_amdgcn_mfma_f32_32x32x16_bf16(af[mi], bfr[ni], acc[mi][ni], 0, 0, 0);
    }
  }

  // ---- epilogues (C layout: col = l32, row = (reg&3) + 8*(reg>>2) + 4*khalf) ----
  if (MODE == MODE_PART) {
    bf16* dst = (bf16*)outp + (size_t)blockIdx.z * M * N;
#pragma unroll
    for (int mi = 0; mi < 2; ++mi)
#pragma unroll
      for (int ni = 0; ni < 2; ++ni) {
        int col = bn + waveN + ni * 32 + l32;
#pragma unroll
        for (int reg = 0; reg < 16; ++reg) {
          int row = bm + waveM + mi * 32 + (reg & 3) + 8 * (reg >> 2) + 4 * khalf;
          dst[(size_t)row * N + col] = __float2bfloat16(acc[mi][ni][reg]);
        }
      }
  } else if (MODE == MODE_GELU) {
    float bcol[2];
#pragma unroll
    for (int ni = 0; ni < 2; ++ni) bcol[ni] = bias[bn + waveN + ni * 32 + l32];
#pragma unroll
    for (int mi = 0; mi < 2; ++mi)
#pragma unroll
      for (int ni = 0; ni < 2; ++ni) {
        int col = bn + waveN + ni * 32 + l32;
#pragma unroll
        for (int reg = 0; reg < 16; ++reg) {
          int row = bm + waveM + mi * 32 + (reg & 3) + 8 * (reg >> 2) + 4 * khalf;
          ((bf16*)outp)[(size_t)row * N + col] =
              __float2bfloat16(gelu_f(acc[mi][ni][reg] + bcol[ni]));
        }
      }
  } else {  // MODE_QKV: seg block-uniform; q -> (b,h,t,d); k -> Kf frag; v -> Vf frag
    int seg = bn >> 10;
    int c1b = (bn & (NC - 1)) + waveN;
    const float* bp = (seg == 0) ? bias : (seg == 1) ? bias2 : bias3;
    float bcol[2]; int hh[2], dd[2];
#pragma unroll
    for (int ni = 0; ni < 2; ++ni) {
      int c1 = c1b + ni * 32 + l32;
      bcol[ni] = bp[c1]; hh[ni] = c1 >> 6; dd[ni] = c1 & (HD - 1);
    }
    if (seg == 0) {
      bf16* dst = (bf16*)outp;
#pragma unroll
      for (int mi = 0; mi < 2; ++mi)
#pragma unroll
        for (int reg = 0; reg < 16; ++reg) {
          int row = bm + waveM + mi * 32 + (reg & 3) + 8 * (reg >> 2) + 4 * khalf;
          int bbi = row >> 11, t = row & (TSEQ - 1);
#pragma unroll
          for (int ni = 0; ni < 2; ++ni)
            dst[((size_t)(bbi * NH + hh[ni]) * TSEQ + t) * HD + dd[ni]] =
                __float2bfloat16(acc[mi][ni][reg] + bcol[ni]);
        }
    } else if (seg == 1) {
      // Kf[bh][kt(64)][ds(4)][lane(64)][8]: lane=hf*32+l31 holds
      // K[kt*32+l31][ds*16+hf*8+j]
      bf16* dst = (bf16*)out2;
#pragma unroll
      for (int mi = 0; mi < 2; ++mi)
#pragma unroll
        for (int reg = 0; reg < 16; ++reg) {
          int row = bm + waveM + mi * 32 + (reg & 3) + 8 * (reg >> 2) + 4 * khalf;
          int bbi = row >> 11, t = row & (TSEQ - 1);
          int kt = t >> 5, lk = t & 31;
#pragma unroll
          for (int ni = 0; ni < 2; ++ni) {
            int d = dd[ni];
            size_t off = ((((size_t)(bbi * NH + hh[ni]) * 64 + kt) * 4 + (d >> 4)) * 64
                          + ((d >> 3) & 1) * 32 + lk) * 8 + (d & 7);
            dst[off] = __float2bfloat16(acc[mi][ni][reg] + bcol[ni]);
          }
        }
    } else {
      // Vf[bh][kt(64)][dt(2)][ks(2)][lane(64)][8]: lane=hf*32+l31 holds
      // V[kt*32+ks*16+hf*8+j][dt*32+l31]
      bf16* dst = (bf16*)out3;
#pragma unroll
      for (int mi = 0; mi < 2; ++mi)
#pragma unroll
        for (int reg = 0; reg < 16; ++reg) {
          int row = bm + waveM + mi * 32 + (reg & 3) + 8 * (reg >> 2) + 4 * khalf;
          int bbi = row >> 11, t = row & (TSEQ - 1);
          int kt = t >> 5, rem = t & 31;
          int ks = rem >> 4, hf = (rem >> 3) & 1, j = rem & 7;
#pragma unroll
          for (int ni = 0; ni < 2; ++ni) {
            int d = dd[ni];
            size_t off = (((((size_t)(bbi * NH + hh[ni]) * 64 + kt) * 2 + (d >> 5)) * 2 + ks) * 64
                          + hf * 32 + (d & 31)) * 8 + j;
            dst[off] = __float2bfloat16(acc[mi][ni][reg] + bcol[ni]);
          }
        }
    }
  }
}

// ---------------- Flash attention v6: swapped-QK^T 32x32, split-K x4, frag-layout K/V ----
// One BLOCK (4 waves) per 32-row q-tile; wave w handles key-tiles kt ≡ w (mod 4).
// K/V are pre-scattered into MFMA fragment order by the QKV GEMM epilogue, so every
// hot load is base + lane*16B (64 lanes = 1KB contiguous -> fully coalesced; fixes
// the per-CU TA gather bottleneck that pinned v4/v5 at ~73us). Swapped S^T=mfma(K,Q)
// keeps q lane-local; P->A-frag via 8 cvt_pk + 4 permlane32_swap. Partials combined
// via 2-round LDS tree.
__global__ __launch_bounds__(256)
void attn_kernel(const bf16* __restrict__ q, const bf16* __restrict__ kf,
                 const bf16* __restrict__ vf, bf16* __restrict__ out) {
  int id  = blockIdx.x;            // 0..2047
  int xcd = id & 7;
  int t   = id >> 3;               // per-XCD arrival index 0..255
  int bh  = xcd * 4 + (t & 3);
  int u   = t >> 2;                // 0..63
  int qt  = (u < 32) ? (2 * u) : (63 - 2 * (u - 32));
  int b = bh >> 4, h = bh & 15;

  int tid  = threadIdx.x;
  int w    = tid >> 6;             // split-K wave 0..3
  int lane = tid & 63;
  int l31  = lane & 31;
  int hh   = lane >> 5;            // 0/1
  int h8   = hh * 8;
  int base4 = hh * 4;

  const bf16* qp  = q  + (size_t)(b * NH + h) * TSEQ * HD;
  const bf16* kfb = kf + (size_t)bh * (64 * 4 * 64 * 8);   // 256KB per (b,h)
  const bf16* vfb = vf + (size_t)bh * (64 * 2 * 2 * 64 * 8);

  int q0 = qt * 32;

  // Q fragments (B-operand): lane holds Q[q0+l31][ds*16 + h8 .. +7]
  bf16x8 qf[4];
#pragma unroll
  for (int ds = 0; ds < 4; ++ds)
    qf[ds] = *(const bf16x8*)(qp + (size_t)(q0 + l31) * HD + ds * 16 + h8);

  f32x16 o0, o1;
#pragma unroll
  for (int r = 0; r < 16; ++r) { o0[r] = 0.f; o1[r] = 0.f; }
  float lacc = 0.f;

  bf16x8 a0, a1, a2, a3;           // K fragments (A-operand), pipelined

  auto step = [&](int kt, bool dg) {
    // V fragments: Vf[kt][dt][ks][lane][8] — contiguous per wave
    const bf16* vs = vfb + (size_t)kt * 2048 + lane * 8;
    bf16x8 v00 = *(const bf16x8*)(vs);            // dt0 ks0
    bf16x8 v01 = *(const bf16x8*)(vs + 512);      // dt0 ks1
    bf16x8 v10 = *(const bf16x8*)(vs + 1024);     // dt1 ks0
    bf16x8 v11 = *(const bf16x8*)(vs + 1536);     // dt1 ks1
    // prefetch K for kt+4 (hidden under QK + softmax)
    bf16x8 n0, n1, n2, n3;
    bool pf = !dg && (kt + 4 <= qt);
    if (pf) {
      const bf16* kn = kfb + (size_t)(kt + 4) * 2048 + lane * 8;
      n0 = *(const bf16x8*)(kn);
      n1 = *(const bf16x8*)(kn + 512);
      n2 = *(const bf16x8*)(kn + 1024);
      n3 = *(const bf16x8*)(kn + 1536);
    }

    f32x16 c;
#pragma unroll
    for (int r = 0; r < 16; ++r) c[r] = 0.f;
    c = __builtin_amdgcn_mfma_f32_32x32x16_bf16(a0, qf[0], c, 0, 0, 0);
    c = __builtin_amdgcn_mfma_f32_32x32x16_bf16(a1, qf[1], c, 0, 0, 0);
    c = __builtin_amdgcn_mfma_f32_32x32x16_bf16(a2, qf[2], c, 0, 0, 0);
    c = __builtin_amdgcn_mfma_f32_32x32x16_bf16(a3, qf[3], c, 0, 0, 0);

    // softmax: p = exp(S/8 - 8) = exp2(S*0.125*log2e - 8*log2e); q is lane-local
    float p[16];
    float ls = 0.f;
#pragma unroll
    for (int r = 0; r < 16; ++r) {
      float pv = exp2f(fmaf(c[r], 0.18033688011112042f, -11.541560327111707f));
      if (dg) {
        int krr = (r & 3) + 8 * (r >> 2) + base4;
        pv = (krr <= l31) ? pv : 0.f;
      }
      p[r] = pv;
      ls += pv;
    }
    lacc += ls;

    // P (f32, key=kr(r,hh)) -> PV A-fragments.
    // swap(vdst=pk(p0,p1), src=pk(p4,p5)): new-vdst = frag word0, new-src = word2
    // (vdst_hi <-> src_lo). Same pattern for words 1/3 and the second chunk.
    unsigned A0 = cvtpk(p[0],  p[1]),  C0 = cvtpk(p[4],  p[5]);
    unsigned B0 = cvtpk(p[2],  p[3]),  D0 = cvtpk(p[6],  p[7]);
    pl32swap(A0, C0); pl32swap(B0, D0);
    unsigned A1 = cvtpk(p[8],  p[9]),  C1 = cvtpk(p[12], p[13]);
    unsigned B1 = cvtpk(p[10], p[11]), D1 = cvtpk(p[14], p[15]);
    pl32swap(A1, C1); pl32swap(B1, D1);
    u32x4 w0v = {A0, B0, C0, D0};
    u32x4 w1v = {A1, B1, C1, D1};
    bf16x8 pa0 = __builtin_bit_cast(bf16x8, w0v);
    bf16x8 pa1 = __builtin_bit_cast(bf16x8, w1v);

    o0 = __builtin_amdgcn_mfma_f32_32x32x16_bf16(pa0, v00, o0, 0, 0, 0);
    o0 = __builtin_amdgcn_mfma_f32_32x32x16_bf16(pa1, v01, o0, 0, 0, 0);
    o1 = __builtin_amdgcn_mfma_f32_32x32x16_bf16(pa0, v10, o1, 0, 0, 0);
    o1 = __builtin_amdgcn_mfma_f32_32x32x16_bf16(pa1, v11, o1, 0, 0, 0);

    if (pf) { a0 = n0; a1 = n1; a2 = n2; a3 = n3; }
  };

  if (w <= qt) {
    const bf16* ka = kfb + (size_t)w * 2048 + lane * 8;
    a0 = *(const bf16x8*)(ka);
    a1 = *(const bf16x8*)(ka + 512);
    a2 = *(const bf16x8*)(ka + 1024);
    a3 = *(const bf16x8*)(ka + 1536);
    int diag = (w == (qt & 3)) ? 1 : 0;   // diag implies w <= qt
    int T = ((qt - w) >> 2) + 1 - diag;   // non-diag step count
    int kt = w;
    for (int i = 0; i < T; ++i, kt += 4) step(kt, false);
    if (diag) step(qt, true);
  }

  // ---- cross-wave combine: 2-round LDS tree (33-float stride: conflict-free) ----
  __shared__ float red[2][64][33];
  auto dump = [&](int slot) {
    float* d = &red[slot][lane][0];
#pragma unroll
    for (int r = 0; r < 16; ++r) { d[r] = o0[r]; d[16 + r] = o1[r]; }
    d[32] = lacc;
  };
  auto gather = [&](int slot) {
    const float* s = &red[slot][lane][0];
#pragma unroll
    for (int r = 0; r < 16; ++r) { o0[r] += s[r]; o1[r] += s[16 + r]; }
    lacc += s[32];
  };
  if (w >= 2) dump(w - 2);
  __syncthreads();
  if (w < 2) gather(w);
  __syncthreads();
  if (w == 1) dump(0);
  __syncthreads();
  if (w == 0) {
    gather(0);
    // normalize: lane l holds denom-half for q-row l31; combine across halves
    float ltot = lacc + __shfl_xor(lacc, 32);
    float linv = 1.0f / ltot;
#pragma unroll
    for (int r = 0; r < 16; ++r) {
      int qoff = (r & 3) + 8 * (r >> 2) + base4;
      float sc = __shfl(linv, qoff);
      size_t ob = ((size_t)(b * TSEQ + q0 + qoff)) * NC + h * HD + l31;
      out[ob]      = __float2bfloat16(o0[r] * sc);
      out[ob + 32] = __float2bfloat16(o1[r] * sc);
    }
  }
}

extern "C" void kernel_launch(void* const* d_in, const int* in_sizes, int n_in,
                              void* d_out, int out_size, void* d_ws, size_t ws_size,
                              hipStream_t stream) {
  const float* x     = (const float*)d_in[0];
  const float* ln1_g = (const float*)d_in[1];
  const float* ln1_b = (const float*)d_in[2];
  const float* Wq    = (const float*)d_in[3];
  const float* bq    = (const float*)d_in[4];
  const float* Wk    = (const float*)d_in[5];
  const float* bk    = (const float*)d_in[6];
  const float* Wv    = (const float*)d_in[7];
  const float* bv    = (const float*)d_in[8];
  const float* Wo    = (const float*)d_in[9];
  const float* bo    = (const float*)d_in[10];
  const float* ln2_g = (const float*)d_in[11];
  const float* ln2_b = (const float*)d_in[12];
  const float* W1    = (const float*)d_in[13];
  const float* b1    = (const float*)d_in[14];
  const float* W2    = (const float*)d_in[15];
  const float* b2    = (const float*)d_in[16];

  char* ws = (char*)d_ws;
  const size_t MB = 1u << 20;
  bf16* WqkvT = (bf16*)(ws + 0 * MB);   // 4x1024x1024 (q|k|v|o)
  bf16* W1T  = (bf16*)(ws + 8 * MB);    // 4096x1024
  bf16* W2T  = (bf16*)(ws + 16 * MB);   // 1024x4096
  bf16* xn1  = (bf16*)(ws + 24 * MB);   // 4096x1024
  bf16* qb   = (bf16*)(ws + 32 * MB);   // (b,h,t,d)        [dead after attn]
  bf16* kfB  = (bf16*)(ws + 40 * MB);   // K fragment layout [dead after attn]
  bf16* vfB  = (bf16*)(ws + 48 * MB);   // V fragment layout [dead after attn]
  bf16* att  = (bf16*)(ws + 56 * MB);   // 4096x1024        [dead after Wo gemm]
  float* x2  = (float*)(ws + 64 * MB);  // 4096x1024 fp32
  bf16* xn2  = (bf16*)(ws + 80 * MB);   // 4096x1024
  bf16* h1   = (bf16*)(ws + 88 * MB);   // 4096x4096        [written after woP consumed]
  bf16* woP  = (bf16*)(ws + 88 * MB);   // 2x 4096x1024 Wo partials (reuses h1 region)
  bf16* w2P  = (bf16*)(ws + 32 * MB);   // 4x 4096x1024 W2 partials (reuses q/k/v/att)
  bf16* WoT  = WqkvT + 3 * (size_t)NC * NC;

  transpose_all_kernel<<<12288, dim3(32, 8), 0, stream>>>(
      Wq, Wk, Wv, Wo, W1, W2, WqkvT, W1T, W2T);

  ln_cast_kernel<<<NROWS, 256, 0, stream>>>(x, ln1_g, ln1_b, xn1);

  gemm_bt<MODE_QKV><<<dim3(24, 32, 1), 256, 0, stream>>>(
      xn1, WqkvT, bq, bk, bv, qb, kfB, vfB, NROWS, 3 * NC, NC, NC);

  attn_kernel<<<2048, 256, 0, stream>>>(qb, kfB, vfB, att);

  gemm_bt<MODE_PART><<<dim3(8, 32, 2), 256, 0, stream>>>(
      att, WoT, nullptr, nullptr, nullptr, woP, nullptr, nullptr, NROWS, NC, NC, NC / 2);

  wo_ln_kernel<<<NROWS, 256, 0, stream>>>(x, bo, woP, ln2_g, ln2_b, x2, xn2);

  gemm_bt<MODE_GELU><<<dim3(32, 32, 1), 256, 0, stream>>>(
      xn2, W1T, b1, nullptr, nullptr, h1, nullptr, nullptr, NROWS, DFF, NC, NC);

  gemm_bt<MODE_PART><<<dim3(8, 32, 4), 256, 0, stream>>>(
      h1, W2T, nullptr, nullptr, nullptr, w2P, nullptr, nullptr, NROWS, NC, DFF, DFF / 4);

  w2_final_kernel<<<NROWS, 256, 0, stream>>>(x2, b2, w2P, (float*)d_out);
}